// Round 6
// baseline (351.535 us; speedup 1.0000x reference)
//
#include <hip/hip_runtime.h>
#include <hip/hip_bf16.h>
#include <stdint.h>

#define B_SZ 8192
#define D_SZ 1024
#define H_SZ 1024
#define O_SZ 512
#define E_SZ 8

typedef float f32x4 __attribute__((ext_vector_type(4)));
typedef float f32x16 __attribute__((ext_vector_type(16)));
typedef __bf16 bf16x8 __attribute__((ext_vector_type(8)));

typedef __attribute__((address_space(1))) uint32_t gu32;
typedef __attribute__((address_space(3))) uint32_t lu32;

__device__ __forceinline__ unsigned short f2bf(float f) {
    union { __hip_bfloat16 h; unsigned short u; } c;
    c.h = __float2bfloat16(f);
    return c.u;
}
__device__ __forceinline__ float bf2f(unsigned short u) {
    union { float f; uint32_t u; } c;
    c.u = ((uint32_t)u) << 16;
    return c.f;
}

// ------- fused: convert x row to bf16 AND compute 20 gate logits + 3 softmaxes -------
// 4 waves/block, one x-row per wave. Lane l handles 4 consecutive floats per step.
__global__ __launch_bounds__(256) void k_convert_gates(const float* __restrict__ x,
                                                       const float* __restrict__ Wg,
                                                       const float* __restrict__ Wgs,
                                                       unsigned short* __restrict__ x_bf,
                                                       float* __restrict__ g_all) {
    const int wv = threadIdx.x >> 6;
    const int lane = threadIdx.x & 63;
    const int b = blockIdx.x * 4 + wv;
    const float* xr = x + (size_t)b * D_SZ;
    unsigned short* xo = x_bf + (size_t)b * D_SZ;
    float acc[20];
#pragma unroll
    for (int j = 0; j < 20; ++j) acc[j] = 0.f;
#pragma unroll
    for (int it = 0; it < 4; ++it) {
        const int d0 = (it * 64 + lane) * 4;
        float4 xv = *(const float4*)(xr + d0);
        ushort4 o;
        o.x = f2bf(xv.x); o.y = f2bf(xv.y); o.z = f2bf(xv.z); o.w = f2bf(xv.w);
        *(ushort4*)(xo + d0) = o;
        const float* pv = (const float*)&xv;
#pragma unroll
        for (int c = 0; c < 4; ++c) {
            const int d = d0 + c;
            const float v = pv[c];
            const float* w0 = Wg + (size_t)d * 6;
            const float* w1 = Wg + (size_t)D_SZ * 6 + (size_t)d * 6;
            const float* ws = Wgs + (size_t)d * 8;
#pragma unroll
            for (int j = 0; j < 6; ++j) acc[j] += v * w0[j];
#pragma unroll
            for (int j = 0; j < 6; ++j) acc[6 + j] += v * w1[j];
#pragma unroll
            for (int j = 0; j < 8; ++j) acc[12 + j] += v * ws[j];
        }
    }
#pragma unroll
    for (int j = 0; j < 20; ++j) {
        float v = acc[j];
#pragma unroll
        for (int s = 32; s > 0; s >>= 1) v += __shfl_down(v, s, 64);
        acc[j] = v;
    }
    if (lane == 0) {
        float* g = g_all + (size_t)b * 20;
#pragma unroll
        for (int t = 0; t < 3; ++t) {
            int base = (t == 0) ? 0 : (t == 1 ? 6 : 12);
            int cnt  = (t == 2) ? 8 : 6;
            float m = -1e30f;
            for (int j = 0; j < cnt; ++j) m = fmaxf(m, acc[base + j]);
            float ex[8]; float sum = 0.f;
            for (int j = 0; j < cnt; ++j) { ex[j] = __expf(acc[base + j] - m); sum += ex[j]; }
            float inv = 1.f / sum;
            for (int j = 0; j < cnt; ++j) g[base + j] = ex[j] * inv;
        }
    }
}

// ------- transpose+convert: in [E][R][C] f32 -> out [E][C][R] bf16 -------
__global__ __launch_bounds__(512) void k_transpose_convert(const float* __restrict__ in,
                                                           unsigned short* __restrict__ out,
                                                           int R, int C) {
    __shared__ float tile[64][65];
    const float* src = in + (size_t)blockIdx.z * R * C;
    unsigned short* dst = out + (size_t)blockIdx.z * R * C;
    int c0 = blockIdx.x * 64, r0 = blockIdx.y * 64;
    int tx = threadIdx.x, ty = threadIdx.y;   // block (64,8)
#pragma unroll
    for (int rr = ty; rr < 64; rr += 8)
        tile[rr][tx] = src[(size_t)(r0 + rr) * C + c0 + tx];
    __syncthreads();
#pragma unroll
    for (int rr = ty; rr < 64; rr += 8)
        dst[(size_t)(c0 + rr) * R + r0 + tx] = f2bf(tile[tx][rr]);
}

// ---------------- 256x256 deep-pipelined bf16 GEMM, BK=32, 4 LDS buffers ----------------
// Same verified pipeline as rounds 3-5 (ring of 4, stage t+3, counted vmcnt,
// 1 barrier/tile, linear glds dest + inverse-swizzled source). MFMA shape
// switched to 32x32x16 (higher pipe rate, half the instruction count).
// Per-wave output 128x64 = acc[4][2] f32x16. 16 MFMA + 12 ds_read_b128/tile/wave.
// A-frag: row=lane&31, k=(lane>>5)*8; B-frag: col=lane&31, k=(lane>>5)*8.
// C/D: col=lane&31, row=(reg&3)+8*(reg>>2)+4*(lane>>5)   [m74/m101 verified].
__global__ __launch_bounds__(512, 2) void k_gemm4(
    const unsigned short* __restrict__ A,
    const unsigned short* __restrict__ Bt,
    const float* __restrict__ bias,
    unsigned short* __restrict__ C,
    int M, int N, int K,
    long long sA, long long sB, long long sBias, long long sC, int e_base) {

    const int tid = threadIdx.x;
    const int lane = tid & 63, wid = tid >> 6;
    const int wr = wid >> 2, wc = wid & 3;       // 2 x 4 wave grid
    const int lr32 = lane & 31, hi = lane >> 5;

    // bijective XCD swizzle on flat grid (nwg % 8 == 0 for all launches here)
    const int nwg = gridDim.x;
    const int wg = blockIdx.x;
    const int swz = (wg & 7) * (nwg >> 3) + (wg >> 3);
    const int nx = N >> 8;
    const int my = M >> 8;
    const int bx = swz % nx;
    const int t1 = swz / nx;
    const int by = t1 % my;
    const int e  = t1 / my + e_base;

    A    += (size_t)((long long)e * sA);
    Bt   += (size_t)((long long)e * sB);
    bias += (size_t)((long long)e * sBias);
    C    += (size_t)((long long)e * sC);

    const int m0 = by * 256, n0 = bx * 256;

    __shared__ __align__(16) unsigned short lds[65536];   // 128 KiB
    char* ldsb = (char*)lds;

    // staging: 512 thr x 16 B = one 8 KiB half (128 rows x 32 cols bf16), linear dest.
    // physical (row, blk) holds source col-block blk ^ ((row>>1)&3)  (blk = 8-elem group)
    const int srow = tid >> 2;
    const int scol = (((tid & 3) ^ ((tid >> 3) & 3)) * 8);
    const int sdst = tid * 16;

    auto stageA = [&](int t) {
        const int bb = (t & 3) * 32768;
        const unsigned short* s0 = A + (size_t)(m0 + srow) * K + (t << 5) + scol;
        __builtin_amdgcn_global_load_lds((gu32*)s0, (lu32*)(ldsb + bb + sdst), 16, 0, 0);
        __builtin_amdgcn_global_load_lds((gu32*)(s0 + (size_t)128 * K),
                                         (lu32*)(ldsb + bb + 8192 + sdst), 16, 0, 0);
    };
    auto stageB = [&](int t) {
        const int bb = (t & 3) * 32768 + 16384;
        const unsigned short* s0 = Bt + (size_t)(n0 + srow) * K + (t << 5) + scol;
        __builtin_amdgcn_global_load_lds((gu32*)s0, (lu32*)(ldsb + bb + sdst), 16, 0, 0);
        __builtin_amdgcn_global_load_lds((gu32*)(s0 + (size_t)128 * K),
                                         (lu32*)(ldsb + bb + 8192 + sdst), 16, 0, 0);
    };

    // fragment read constants (byte offsets); swizzle term depends only on lr32
    const int sxor = (lr32 >> 1) & 3;
    const int cblk0 = ((0 * 2 + hi) ^ sxor) * 16;     // k-sub 0
    const int cblk1 = ((1 * 2 + hi) ^ sxor) * 16;     // k-sub 1
    const int aoff = wr * 8192 + lr32 * 64;
    const int boff = 16384 + (wc >> 1) * 8192 + (wc & 1) * 4096 + lr32 * 64;

    // frags: f[0..7] = A (mi*2+ks), f[8..11] = B (nj*2+ks)
    auto loadf = [&](bf16x8* f, int bb) {
#pragma unroll
        for (int mi = 0; mi < 4; ++mi) {
            f[mi * 2 + 0] = *(const bf16x8*)(ldsb + bb + aoff + mi * 2048 + cblk0);
            f[mi * 2 + 1] = *(const bf16x8*)(ldsb + bb + aoff + mi * 2048 + cblk1);
        }
#pragma unroll
        for (int nj = 0; nj < 2; ++nj) {
            f[8 + nj * 2 + 0] = *(const bf16x8*)(ldsb + bb + boff + nj * 2048 + cblk0);
            f[8 + nj * 2 + 1] = *(const bf16x8*)(ldsb + bb + boff + nj * 2048 + cblk1);
        }
    };

    f32x16 acc[4][2];
#pragma unroll
    for (int i = 0; i < 4; ++i)
#pragma unroll
        for (int j = 0; j < 2; ++j)
            acc[i][j] = (f32x16)(0.f);

    auto domfma = [&](const bf16x8* f) {
        __builtin_amdgcn_s_setprio(1);
#pragma unroll
        for (int mi = 0; mi < 4; ++mi)
#pragma unroll
            for (int nj = 0; nj < 2; ++nj) {
                acc[mi][nj] = __builtin_amdgcn_mfma_f32_32x32x16_bf16(
                    f[mi * 2 + 0], f[8 + nj * 2 + 0], acc[mi][nj], 0, 0, 0);
                acc[mi][nj] = __builtin_amdgcn_mfma_f32_32x32x16_bf16(
                    f[mi * 2 + 1], f[8 + nj * 2 + 1], acc[mi][nj], 0, 0, 0);
            }
        __builtin_amdgcn_s_setprio(0);
    };

    const int NT = K >> 5;   // 32 (even, >= 8)

    // prologue: stage tiles 0,1,2 (12 glds); wait tiles 0,1 landed (leave tile 2's 4)
    stageA(0); stageB(0); stageA(1); stageB(1); stageA(2); stageB(2);
    asm volatile("s_waitcnt vmcnt(4)" ::: "memory");
    asm volatile("s_barrier" ::: "memory");

    bf16x8 fA[12], fB[12];
    loadf(fA, 0);

    for (int t = 0; t < NT; t += 2) {
        // ---- even tile t: consume fA(t); load fB(t+1); stage t+3 ----
        if (t + 3 < NT) { stageA(t + 3); stageB(t + 3); }
        loadf(fB, ((t + 1) & 3) * 32768);        // buf t+1 landed (prev boundary)
        domfma(fA);
        if (t + 3 < NT)      { asm volatile("s_waitcnt vmcnt(4)" ::: "memory"); }
        else if (t + 2 < NT) { asm volatile("s_waitcnt vmcnt(0)" ::: "memory"); }
        asm volatile("s_barrier" ::: "memory");

        // ---- odd tile t+1: consume fB(t+1); load fA(t+2); stage t+4 ----
        if (t + 4 < NT) { stageA(t + 4); stageB(t + 4); }
        if (t + 2 < NT) loadf(fA, ((t + 2) & 3) * 32768);
        domfma(fB);
        if (t + 4 < NT)      { asm volatile("s_waitcnt vmcnt(4)" ::: "memory"); }
        else if (t + 3 < NT) { asm volatile("s_waitcnt vmcnt(0)" ::: "memory"); }
        asm volatile("s_barrier" ::: "memory");
    }

    // ---- epilogue: bias + relu -> LDS-staged bf16 tile -> coalesced dwordx4 stores ----
    unsigned short* ct = (unsigned short*)ldsb;
#pragma unroll
    for (int nj = 0; nj < 2; ++nj) {
        const int nn = wc * 64 + nj * 32 + lr32;
        const float bv = bias[n0 + nn];
#pragma unroll
        for (int mi = 0; mi < 4; ++mi) {
#pragma unroll
            for (int r = 0; r < 16; ++r) {
                const int mloc = wr * 128 + mi * 32 + (r & 3) + 8 * (r >> 2) + 4 * hi;
                float v = fmaxf(acc[mi][nj][r] + bv, 0.f);
                ct[(size_t)mloc * 256 + nn] = f2bf(v);
            }
        }
    }
    __syncthreads();
#pragma unroll
    for (int it = 0; it < 16; ++it) {
        const int row = it * 16 + (tid >> 5);
        const int colE = (tid & 31) * 8;
        *(int4*)(&C[(size_t)(m0 + row) * N + n0 + colE]) =
            *(const int4*)(ldsb + it * 8192 + (size_t)tid * 16);
    }
}

// ---------------- combine: out[b][t][o], 4 o's per thread ----------------
__global__ __launch_bounds__(256) void k_combine(const unsigned short* __restrict__ eo,
                                                 const float* __restrict__ g_all,
                                                 float* __restrict__ out) {
    int idx4 = blockIdx.x * 256 + threadIdx.x;    // over B*O/4
    int b = idx4 >> 7;                            // O/4 = 128
    int o4 = (idx4 & 127) * 4;
    const float* g = g_all + (size_t)b * 20;
    float v[E_SZ][4];
#pragma unroll
    for (int e = 0; e < E_SZ; ++e) {
        ushort4 u = *(const ushort4*)(eo + (size_t)e * B_SZ * O_SZ + (size_t)b * O_SZ + o4);
        v[e][0] = bf2f(u.x); v[e][1] = bf2f(u.y); v[e][2] = bf2f(u.z); v[e][3] = bf2f(u.w);
    }
    float4 r0, r1, r2;
    float* p0 = (float*)&r0; float* p1 = (float*)&r1; float* p2 = (float*)&r2;
#pragma unroll
    for (int c = 0; c < 4; ++c) {
        p0[c] = g[0] * v[0][c] + g[1] * v[1][c] + g[2] * v[4][c] + g[3] * v[5][c]
              + g[4] * v[6][c] + g[5] * v[7][c];
        p1[c] = g[6] * v[2][c] + g[7] * v[3][c] + g[8] * v[4][c] + g[9] * v[5][c]
              + g[10] * v[6][c] + g[11] * v[7][c];
        float s = 0.f;
#pragma unroll
        for (int e = 0; e < E_SZ; ++e) s += g[12 + e] * v[e][c];
        p2[c] = s;
    }
    size_t ob = (size_t)b * (3 * O_SZ) + o4;
    *(float4*)(out + ob) = r0;
    *(float4*)(out + ob + O_SZ) = r1;
    *(float4*)(out + ob + 2 * O_SZ) = r2;
}

extern "C" void kernel_launch(void* const* d_in, const int* in_sizes, int n_in,
                              void* d_out, int out_size, void* d_ws, size_t ws_size,
                              hipStream_t stream) {
    const float* x   = (const float*)d_in[0];
    const float* W1  = (const float*)d_in[1];
    const float* b1  = (const float*)d_in[2];
    const float* W2  = (const float*)d_in[3];
    const float* b2  = (const float*)d_in[4];
    const float* Wg  = (const float*)d_in[5];
    const float* Wgs = (const float*)d_in[6];
    float* out = (float*)d_out;

    char* ws = (char*)d_ws;
    const size_t SZ_XBF  = (size_t)B_SZ * D_SZ * 2;           // 16 MB
    const size_t SZ_W1T  = (size_t)E_SZ * H_SZ * D_SZ * 2;    // 16 MB
    const size_t SZ_W2T  = (size_t)E_SZ * O_SZ * H_SZ * 2;    // 8 MB
    const size_t SZ_EO   = (size_t)E_SZ * B_SZ * O_SZ * 2;    // 64 MB
    const size_t SZ_G    = (size_t)B_SZ * 20 * 4;             // 640 KB
    const size_t SZ_HBIG = (size_t)E_SZ * B_SZ * H_SZ * 2;    // 128 MB

    unsigned short* x_bf = (unsigned short*)ws;              ws += SZ_XBF;
    unsigned short* W1T  = (unsigned short*)ws;              ws += SZ_W1T;
    unsigned short* W2T  = (unsigned short*)ws;              ws += SZ_W2T;
    unsigned short* eo   = (unsigned short*)ws;              ws += SZ_EO;
    float* g_all         = (float*)ws;                       ws += SZ_G;
    unsigned short* h_buf = (unsigned short*)ws;

    const size_t fixed = SZ_XBF + SZ_W1T + SZ_W2T + SZ_EO + SZ_G;
    const bool big = ws_size >= fixed + SZ_HBIG;

    // 1) fused convert + gates; weight transposes
    k_convert_gates<<<B_SZ / 4, 256, 0, stream>>>(x, Wg, Wgs, x_bf, g_all);
    dim3 tb(64, 8);
    k_transpose_convert<<<dim3(H_SZ / 64, D_SZ / 64, E_SZ), tb, 0, stream>>>(W1, W1T, D_SZ, H_SZ);
    k_transpose_convert<<<dim3(O_SZ / 64, H_SZ / 64, E_SZ), tb, 0, stream>>>(W2, W2T, H_SZ, O_SZ);

    // 2) expert GEMMs (256x256 tiles; flat 1D grids, all % 8 == 0)
    if (big) {
        k_gemm4<<<(H_SZ / 256) * (B_SZ / 256) * E_SZ, 512, 0, stream>>>(
            x_bf, W1T, b1, h_buf, B_SZ, H_SZ, D_SZ,
            0LL, (long long)H_SZ * D_SZ, (long long)H_SZ, (long long)B_SZ * H_SZ, 0);
        k_gemm4<<<(O_SZ / 256) * (B_SZ / 256) * E_SZ, 512, 0, stream>>>(
            h_buf, W2T, b2, eo, B_SZ, O_SZ, H_SZ,
            (long long)B_SZ * H_SZ, (long long)O_SZ * H_SZ, (long long)O_SZ, (long long)B_SZ * O_SZ, 0);
    } else {
        for (int e = 0; e < E_SZ; ++e) {
            k_gemm4<<<(H_SZ / 256) * (B_SZ / 256), 512, 0, stream>>>(
                x_bf, W1T, b1, h_buf, B_SZ, H_SZ, D_SZ,
                0LL, (long long)H_SZ * D_SZ, (long long)H_SZ, 0LL, e);
            k_gemm4<<<(O_SZ / 256) * (B_SZ / 256), 512, 0, stream>>>(
                h_buf, W2T, b2, eo, B_SZ, O_SZ, H_SZ,
                0LL, (long long)O_SZ * H_SZ, (long long)O_SZ, (long long)B_SZ * O_SZ, e);
        }
    }

    // 3) combine
    k_combine<<<(B_SZ * O_SZ / 4) / 256, 256, 0, stream>>>(eo, g_all, out);
}